// Round 6
// baseline (559.225 us; speedup 1.0000x reference)
//
#include <hip/hip_runtime.h>
#include <cstddef>

#define CLS 128  // NUM_CLASSES

typedef _Float16 half8 __attribute__((ext_vector_type(8)));
typedef float f32x4 __attribute__((ext_vector_type(4)));

#define GLOAD(g, l)                                                        \
  __builtin_amdgcn_global_load_lds(                                        \
      (const __attribute__((address_space(1))) unsigned int*)(g),          \
      (__attribute__((address_space(3))) unsigned int*)(l), 16, 0, 0)

__device__ inline half8 cvt8(float4 a, float4 b) {
  half8 r;
  r[0] = (_Float16)a.x; r[1] = (_Float16)a.y; r[2] = (_Float16)a.z; r[3] = (_Float16)a.w;
  r[4] = (_Float16)b.x; r[5] = (_Float16)b.y; r[6] = (_Float16)b.z; r[7] = (_Float16)b.w;
  return r;
}

// swizzle helpers: slot s within a row, low-3 bits XORed with row&7.
__device__ inline int swz8(int s, int r) { return (s ^ r) & 7; }
__device__ inline int swz16(int s, int r) { return (s & 8) | ((s ^ r) & 7); }

// ---------------------------------------------------------------------------
// build_groups: bucket rows by type.
// hdr ints: [0..8]=off1 [9..17]=off2 [18..26]=tileOff [27]=totalTiles
//           [28..35]=ntc [36..43]=ntr
// ---------------------------------------------------------------------------
__global__ void build_groups(const int* __restrict__ t1, const int* __restrict__ t2,
                             int n1, int n2, int T,
                             int* __restrict__ idx1, int* __restrict__ idx2,
                             int* __restrict__ hdr) {
  __shared__ int cnt[32];
  __shared__ int cur[32];
  const int* tp = (blockIdx.x == 0) ? t1 : t2;
  int n = (blockIdx.x == 0) ? n1 : n2;
  int* idx = (blockIdx.x == 0) ? idx1 : idx2;
  int* off = hdr + ((blockIdx.x == 0) ? 0 : 9);

  if ((int)threadIdx.x < 32) cnt[threadIdx.x] = 0;
  __syncthreads();
  for (int i = threadIdx.x; i < n; i += blockDim.x) atomicAdd(&cnt[tp[i] & 31], 1);
  __syncthreads();
  if (threadIdx.x == 0) {
    int s = 0;
    for (int p = 0; p < T; ++p) { off[p] = s; cur[p] = s; s += cnt[p]; }
    off[T] = s;
  }
  __syncthreads();
  for (int i = threadIdx.x; i < n; i += blockDim.x) {
    int pos = atomicAdd(&cur[tp[i] & 31], 1);
    idx[pos] = i;
  }
}

__global__ void build_tiles(int T, int* __restrict__ hdr) {
  if (threadIdx.x == 0 && blockIdx.x == 0) {
    const int* off1 = hdr;
    const int* off2 = hdr + 9;
    int* toff = hdr + 18;
    int* ntcA = hdr + 28;
    int* ntrA = hdr + 36;
    int s = 0;
    for (int p = 0; p < T; ++p) {
      int c1 = off1[p + 1] - off1[p];
      int c2 = off2[p + 1] - off2[p];
      int ntr = (c1 + 127) / 128;
      int ntc = (c2 + 127) / 128;
      ntcA[p] = ntc;
      ntrA[p] = ntr;
      toff[p] = s;
      s += ntr * ntc;
    }
    toff[T] = s;
    hdr[27] = s;
  }
}

// ---------------------------------------------------------------------------
// gather_both: one pass per side. Writes
//   G[pos][0..d)  = f16(ft[idx[pos]][:])            (sorted full rows)
//   S[key][0..128) = f16(slot slice of that row),   key = pos (sortedS=1)
//                                                   key = idx[pos] (sortedS=0)
// one thread per 16B chunk (8 f16).
// ---------------------------------------------------------------------------
__global__ void gather_both(const float* __restrict__ ft, const int* __restrict__ idx,
                            const int* __restrict__ types,
                            _Float16* __restrict__ G, _Float16* __restrict__ S,
                            int n, int d, int sortedS) {
  int g = blockIdx.x * blockDim.x + threadIdx.x;
  int per = d >> 3;  // 128 chunks per row
  if (g >= n * per) return;
  int pos = g / per;
  int c = g - pos * per;
  int src_row = idx[pos];
  const float4* s = reinterpret_cast<const float4*>(ft + (size_t)src_row * d + c * 8);
  half8 v = cvt8(s[0], s[1]);
  *reinterpret_cast<half8*>(G + (size_t)pos * d + c * 8) = v;
  int t = types[src_row] & 31;
  if ((c >> 4) == t) {
    int key = sortedS ? pos : src_row;
    *reinterpret_cast<half8*>(S + (size_t)key * CLS + (c & 15) * 8) = v;
  }
}

// ---------------------------------------------------------------------------
// cross_lds: out[idx1[bm+r]][bn+c] = S1s[bm+r][:] . S2h[bn+c][:]  (K=128)
// for DIFFERENT-type pairs only (same-type left to grouped_lds).
// m97 structure: single-shot global_load_lds staging (K=128 fits LDS),
// both-sides XOR swizzle, 4 waves x (64x64), f16 MFMA.
// ---------------------------------------------------------------------------
__global__ __launch_bounds__(256) void cross_lds(
    const _Float16* __restrict__ S1s, const _Float16* __restrict__ S2h,
    const int* __restrict__ idx1,
    const int* __restrict__ t1, const int* __restrict__ t2,
    float* __restrict__ out, int n2) {
  __shared__ _Float16 As[16384];  // 128 rows x 128 k, swizzled, 32KB
  __shared__ _Float16 Bs[16384];
  const int tid = threadIdx.x;
  const int lane = tid & 63, w = tid >> 6;
  const int wr = w >> 1, wc = w & 1;
  const int bm = blockIdx.y * 128, bn = blockIdx.x * 128;

  // stage: 8 GLOADs per thread-wave slot for A, 8 for B.
  // inst n covers rows w*32 + n*4 + (lane>>4), slot = lane&15 (16B slots).
  {
    const int rl = lane >> 4, sl = lane & 15;
#pragma unroll
    for (int n = 0; n < 8; ++n) {
      const int row = w * 32 + n * 4 + rl;
      const _Float16* srcA = S1s + (size_t)(bm + row) * CLS + swz16(sl, row & 7) * 8;
      const _Float16* srcB = S2h + (size_t)(bn + row) * CLS + swz16(sl, row & 7) * 8;
      GLOAD(srcA, As + w * 4096 + n * 512);
      GLOAD(srcB, Bs + w * 4096 + n * 512);
    }
  }
  __syncthreads();

  f32x4 acc[4][4] = {};
  const int fr = lane & 15, fq = lane >> 4;
#pragma unroll
  for (int c = 0; c < 4; ++c) {
    const int s = c * 4 + fq;
    half8 af[4], bf[4];
#pragma unroll
    for (int i = 0; i < 4; ++i) {
      const int ra = wr * 64 + i * 16 + fr;
      af[i] = *reinterpret_cast<const half8*>(As + ra * 128 + swz16(s, ra & 7) * 8);
      const int rb = wc * 64 + i * 16 + fr;
      bf[i] = *reinterpret_cast<const half8*>(Bs + rb * 128 + swz16(s, rb & 7) * 8);
    }
#pragma unroll
    for (int i = 0; i < 4; ++i)
#pragma unroll
      for (int j = 0; j < 4; ++j)
        acc[i][j] = __builtin_amdgcn_mfma_f32_16x16x32_f16(af[i], bf[j], acc[i][j], 0, 0, 0);
  }

  // epilogue: predicated scatter (skip same-type cells)
  int tcol[4];
#pragma unroll
  for (int j = 0; j < 4; ++j) tcol[j] = t2[bn + wc * 64 + j * 16 + fr];
  const int ocol = bn + wc * 64 + fr;
#pragma unroll
  for (int i = 0; i < 4; ++i) {
#pragma unroll
    for (int q = 0; q < 4; ++q) {
      const int pos = bm + wr * 64 + i * 16 + fq * 4 + q;
      const int grow = idx1[pos];
      const int trow = t1[grow];
      float* orow = out + (size_t)grow * n2 + ocol;
#pragma unroll
      for (int j = 0; j < 4; ++j)
        if (tcol[j] != trow) orow[j * 16] = acc[i][j][q];
    }
  }
}

// ---------------------------------------------------------------------------
// grouped_lds: dense per-type GEMM (K=d) on sorted f16 rows. BK=64,
// double-buffered LDS, both-sides XOR swizzle, stage-early pipeline.
// Writes ALL same-type cells. Type -> XCD affinity via blockIdx % T.
// ---------------------------------------------------------------------------
__global__ __launch_bounds__(256) void grouped_lds(
    const _Float16* __restrict__ G1, const _Float16* __restrict__ G2,
    const int* __restrict__ idx1, const int* __restrict__ idx2,
    const int* __restrict__ hdr, float* __restrict__ out,
    int K, int n2, int T, int stride) {
  __shared__ _Float16 As[2][8192];  // 128 rows x 64 k per buffer (16KB)
  __shared__ _Float16 Bs[2][8192];
  const int* off1 = hdr;
  const int* off2 = hdr + 9;
  const int* ntcA = hdr + 28;
  const int* ntrA = hdr + 36;

  const int tid = threadIdx.x;
  const int lane = tid & 63, w = tid >> 6;
  const int wr = w >> 1, wc = w & 1;
  const int p = blockIdx.x % T;
  const int base1 = off1[p], base2 = off2[p];
  const int c1 = off1[p + 1] - base1, c2 = off2[p + 1] - base2;
  const int ntc = ntcA[p];
  const int ntiles = ntrA[p] * ntc;

  const int rl = lane >> 3, sl = lane & 7;  // staging: 8 rows x 8 slots per inst
  const int fr = lane & 15, fq = lane >> 4;

  for (int ti = blockIdx.x / T; ti < ntiles; ti += stride) {
    const int tr = ti / ntc, tc = ti % ntc;
    const int r0 = tr * 128, q0 = tc * 128;

    // per-inst source bases (4 A + 4 B GLOADs per thread per K-step)
    const _Float16* srcA[4];
    const _Float16* srcB[4];
#pragma unroll
    for (int n = 0; n < 4; ++n) {
      const int row = w * 32 + n * 8 + rl;
      srcA[n] = G1 + (size_t)(base1 + r0 + row) * K + swz8(sl, row & 7) * 8;
      srcB[n] = G2 + (size_t)(base2 + q0 + row) * K + swz8(sl, row & 7) * 8;
    }

    f32x4 acc[4][4] = {};
    int cur = 0;

#pragma unroll
    for (int n = 0; n < 4; ++n) {  // prologue: stage K-step 0 into buf 0
      GLOAD(srcA[n], &As[0][0] + w * 2048 + n * 512);
      GLOAD(srcB[n], &Bs[0][0] + w * 2048 + n * 512);
    }
    __syncthreads();

    const int nk = K >> 6;
    for (int ks = 0; ks < nk; ++ks) {
      if (ks + 1 < nk) {  // issue next stage before compute
        const int k0 = (ks + 1) << 6;
#pragma unroll
        for (int n = 0; n < 4; ++n) {
          GLOAD(srcA[n] + k0, &As[cur ^ 1][0] + w * 2048 + n * 512);
          GLOAD(srcB[n] + k0, &Bs[cur ^ 1][0] + w * 2048 + n * 512);
        }
      }
      const _Float16* A = &As[cur][0];
      const _Float16* B = &Bs[cur][0];
#pragma unroll
      for (int c = 0; c < 2; ++c) {
        const int s = c * 4 + fq;
        half8 af[4], bf[4];
#pragma unroll
        for (int i = 0; i < 4; ++i) {
          const int ra = wr * 64 + i * 16 + fr;
          af[i] = *reinterpret_cast<const half8*>(A + ra * 64 + swz8(s, ra & 7) * 8);
          const int rb = wc * 64 + i * 16 + fr;
          bf[i] = *reinterpret_cast<const half8*>(B + rb * 64 + swz8(s, rb & 7) * 8);
        }
#pragma unroll
        for (int i = 0; i < 4; ++i)
#pragma unroll
          for (int j = 0; j < 4; ++j)
            acc[i][j] = __builtin_amdgcn_mfma_f32_16x16x32_f16(af[i], bf[j], acc[i][j], 0, 0, 0);
      }
      __syncthreads();  // drains vmcnt: next buffer staged, this buffer free
      cur ^= 1;
    }

    // scatter epilogue (validated round 2/3): all same-type cells
    int gcols[4];
#pragma unroll
    for (int j = 0; j < 4; ++j) {
      const int cl = wc * 64 + j * 16 + fr;
      gcols[j] = (q0 + cl < c2) ? idx2[base2 + q0 + cl] : -1;
    }
#pragma unroll
    for (int i = 0; i < 4; ++i) {
#pragma unroll
      for (int q = 0; q < 4; ++q) {
        const int rloc = wr * 64 + i * 16 + fq * 4 + q;
        if (r0 + rloc >= c1) continue;
        const int grow = idx1[base1 + r0 + rloc];
        float* orow = out + (size_t)grow * n2;
#pragma unroll
        for (int j = 0; j < 4; ++j)
          if (gcols[j] >= 0) orow[gcols[j]] = acc[i][j][q];
      }
    }
    __syncthreads();  // LDS stable before next tile's prologue
  }
}

// ---------------------------------------------------------------------------
extern "C" void kernel_launch(void* const* d_in, const int* in_sizes, int n_in,
                              void* d_out, int out_size, void* d_ws, size_t ws_size,
                              hipStream_t stream) {
  const float* ft1 = (const float*)d_in[0];
  const float* ft2 = (const float*)d_in[1];
  const int* t1 = (const int*)d_in[2];
  const int* t2 = (const int*)d_in[3];
  float* out = (float*)d_out;

  const int n1 = in_sizes[2];
  const int n2 = in_sizes[3];
  const int d = in_sizes[0] / n1;  // 1024
  const int T = d / CLS;           // 8

  // ws: G1h (n1+128 rows) | G2h (n2+128 rows) | S1s | S2h | idx1 | idx2 | hdr
  const size_t grows1 = (size_t)n1 + 128, grows2 = (size_t)n2 + 128;
  _Float16* G1h = (_Float16*)d_ws;
  _Float16* G2h = G1h + grows1 * d;
  _Float16* S1s = G2h + grows2 * d;
  _Float16* S2h = S1s + (size_t)n1 * CLS;
  int* idx1 = (int*)(S2h + (size_t)n2 * CLS);
  int* idx2 = idx1 + n1;
  int* hdr = idx2 + n2;

  build_groups<<<2, 256, 0, stream>>>(t1, t2, n1, n2, T, idx1, idx2, hdr);
  build_tiles<<<1, 64, 0, stream>>>(T, hdr);

  const int gblocks = (int)(((size_t)n1 * (d / 8) + 255) / 256);
  gather_both<<<gblocks, 256, 0, stream>>>(ft1, idx1, t1, G1h, S1s, n1, d, 1);
  gather_both<<<gblocks, 256, 0, stream>>>(ft2, idx2, t2, G2h, S2h, n2, d, 0);

  dim3 grid(n2 / 128, n1 / 128);
  cross_lds<<<grid, 256, 0, stream>>>(S1s, S2h, idx1, t1, t2, out, n2);
  const int stride = 128;
  grouped_lds<<<T * stride, 256, 0, stream>>>(G1h, G2h, idx1, idx2, hdr, out, d, n2, T, stride);
}